// Round 4
// baseline (251.825 us; speedup 1.0000x reference)
//
#include <hip/hip_runtime.h>
#include <math.h>

// Problem constants
#define BATCH 8
#define NN 64
#define DD 65536          // 64*32*32 feature length (contiguous per [b,n])
#define CH 256            // K-chunks per batch -> grid = 8*256 = 2048 blocks
#define KC (DD / CH)      // 256 K per block
#define KSTEPS (KC / 32)  // 8 MFMA K-steps per block

typedef float  floatx4 __attribute__((ext_vector_type(4)));
typedef __bf16 bf16x8  __attribute__((ext_vector_type(8)));

// Pack 8 fp32 -> 8 bf16 via v_perm_b32 (truncation; bias cancels in the
// scale-invariant cosine ratio — validated R3: absmax 1.5e-5).
static __device__ __forceinline__ bf16x8 cvt8(float4 lo, float4 hi) {
    const unsigned sel = 0x07060302u;
    union { unsigned u[4]; bf16x8 v; } r;
    r.u[0] = __builtin_amdgcn_perm(__float_as_uint(lo.y), __float_as_uint(lo.x), sel);
    r.u[1] = __builtin_amdgcn_perm(__float_as_uint(lo.w), __float_as_uint(lo.z), sel);
    r.u[2] = __builtin_amdgcn_perm(__float_as_uint(hi.y), __float_as_uint(hi.x), sel);
    r.u[3] = __builtin_amdgcn_perm(__float_as_uint(hi.w), __float_as_uint(hi.z), sel);
    return r.v;
}

// ---------------------------------------------------------------------------
// Stage 1: per-chunk partial Gram matrices. NO LDS, NO BARRIERS.
// 2048 blocks x 4 waves (2x R3's TLP). Wave w computes row-band w.
// Explicit register double-buffer: loads for step s+1 are issued before the
// cvt+MFMA of step s consumes buffer s, guaranteeing >=8 dwordx4 in flight
// per wave independent of compiler scheduling conservatism.
// ---------------------------------------------------------------------------
__global__ __launch_bounds__(256, 4) void gram_partial_kernel(const float* __restrict__ a,
                                                              float* __restrict__ part) {
    const int bid = blockIdx.x;
    const int b = bid >> 8;           // / CH
    const int c = bid & (CH - 1);

    const int tid  = threadIdx.x;
    const int w    = tid >> 6;        // wave id 0..3 -> output row band
    const int lane = tid & 63;
    const int m    = lane & 15;
    const int q    = lane >> 4;

    const float* base = a + (size_t)b * NN * DD + (size_t)c * KC
                          + (size_t)m * DD + q * 8;
    const float* p0 = base + (size_t)((w ^ 0) * 16) * DD;  // own band (A operand)
    const float* p1 = base + (size_t)((w ^ 1) * 16) * DD;
    const float* p2 = base + (size_t)((w ^ 2) * 16) * DD;
    const float* p3 = base + (size_t)((w ^ 3) * 16) * DD;

    floatx4 acc[4];
    #pragma unroll
    for (int i = 0; i < 4; ++i) acc[i] = (floatx4)0.0f;

    float4 A0, A1, A2, A3, A4, A5, A6, A7;   // buffer A
    float4 B0, B1, B2, B3, B4, B5, B6, B7;   // buffer B

#define LOADSET(R0,R1,R2,R3,R4,R5,R6,R7, o)                      \
    R0 = *(const float4*)(p0 + (o));  R1 = *(const float4*)(p0 + (o) + 4); \
    R2 = *(const float4*)(p1 + (o));  R3 = *(const float4*)(p1 + (o) + 4); \
    R4 = *(const float4*)(p2 + (o));  R5 = *(const float4*)(p2 + (o) + 4); \
    R6 = *(const float4*)(p3 + (o));  R7 = *(const float4*)(p3 + (o) + 4);

#define MFMASET(R0,R1,R2,R3,R4,R5,R6,R7)                         \
    {                                                            \
        bf16x8 f0 = cvt8(R0, R1);                                \
        bf16x8 f1 = cvt8(R2, R3);                                \
        bf16x8 f2 = cvt8(R4, R5);                                \
        bf16x8 f3 = cvt8(R6, R7);                                \
        acc[0] = __builtin_amdgcn_mfma_f32_16x16x32_bf16(f0, f0, acc[0], 0, 0, 0); \
        acc[1] = __builtin_amdgcn_mfma_f32_16x16x32_bf16(f0, f1, acc[1], 0, 0, 0); \
        acc[2] = __builtin_amdgcn_mfma_f32_16x16x32_bf16(f0, f2, acc[2], 0, 0, 0); \
        acc[3] = __builtin_amdgcn_mfma_f32_16x16x32_bf16(f0, f3, acc[3], 0, 0, 0); \
    }

    LOADSET(A0,A1,A2,A3,A4,A5,A6,A7, 0)
    #pragma unroll
    for (int s = 0; s < KSTEPS; s += 2) {
        if (s + 1 < KSTEPS) { LOADSET(B0,B1,B2,B3,B4,B5,B6,B7, (s + 1) * 32) }
        MFMASET(A0,A1,A2,A3,A4,A5,A6,A7)
        if (s + 2 < KSTEPS) { LOADSET(A0,A1,A2,A3,A4,A5,A6,A7, (s + 2) * 32) }
        if (s + 1 < KSTEPS) { MFMASET(B0,B1,B2,B3,B4,B5,B6,B7) }
    }
#undef LOADSET
#undef MFMASET

    // Tile (w, t=w^i): C/D layout row=(q*4+r), col=m within tile (swap-safe:
    // G symmetric). part[bid] holds 16 tiles of 256 floats at slot (w*4+t).
    float* pg = part + (size_t)bid * (NN * NN);
    #pragma unroll
    for (int i = 0; i < 4; ++i) {
        const int t = w ^ i;
        float* tp = pg + (w * 4 + t) * 256 + m;
        #pragma unroll
        for (int r = 0; r < 4; ++r)
            tp[(q * 4 + r) * 16] = acc[i][r];
    }
}

// ---------------------------------------------------------------------------
// Stage 1b: reduce CH partials per batch -> gram[8][64*64] (row-major i*64+j).
// 256 blocks x 128 threads; thread owns one output element, 4 accumulators
// to keep 4+ loads in flight.
// ---------------------------------------------------------------------------
__global__ __launch_bounds__(128) void gram_reduce_kernel(const float* __restrict__ part,
                                                          float* __restrict__ gram) {
    const int gid = blockIdx.x * 128 + threadIdx.x;   // 0 .. 8*4096-1
    const int b   = gid >> 12;
    const int idx = gid & 4095;
    const int i   = idx >> 6;
    const int j   = idx & 63;
    const int off = ((i >> 4) * 4 + (j >> 4)) * 256 + (i & 15) * 16 + (j & 15);
    const float* p = part + (size_t)b * CH * (NN * NN) + off;

    float s0 = 0.f, s1 = 0.f, s2 = 0.f, s3 = 0.f;
    #pragma unroll 4
    for (int c = 0; c < CH; c += 4) {
        s0 += p[(size_t)(c + 0) * (NN * NN)];
        s1 += p[(size_t)(c + 1) * (NN * NN)];
        s2 += p[(size_t)(c + 2) * (NN * NN)];
        s3 += p[(size_t)(c + 3) * (NN * NN)];
    }
    gram[gid] = (s0 + s1) + (s2 + s3);
}

// ---------------------------------------------------------------------------
// Stage 2: per-batch CRF iterations. 8 blocks x 256 threads.
// ---------------------------------------------------------------------------
__global__ __launch_bounds__(256) void crf_kernel(const float* __restrict__ gram,
                                                  const float* __restrict__ logits,
                                                  const float* __restrict__ Wm,
                                                  float* __restrict__ out) {
    __shared__ float pp[NN][NN + 1];
    __shared__ float E[NN];
    __shared__ float nrm[NN];
    __shared__ float part[4 * NN];

    const int b  = blockIdx.x;
    const int tid = threadIdx.x;
    const int i  = tid & 63;
    const int jq = tid >> 6;
    const float* g = gram + b * NN * NN;

    if (jq == 0) nrm[i] = sqrtf(g[i * NN + i]);
    E[i] = 0.0f;
    __syncthreads();

    const float ni = nrm[i];
    for (int jj = 0; jj < 16; ++jj) {
        int j = jq * 16 + jj;
        float wsym = 0.5f * (Wm[i * NN + j] + Wm[j * NN + i]);
        pp[i][j] = g[i * NN + j] / (ni * nrm[j] + 1e-6f) * wsym;
    }
    const float li = logits[b * NN + i];
    __syncthreads();

    for (int it = 0; it < 10; ++it) {
        float acc = 0.0f;
        for (int jj = 0; jj < 16; ++jj) {
            int j = jq * 16 + jj;
            float t = li + E[j];
            float s = 1.0f / (1.0f + expf(-t));
            acc = fmaf(2.0f * s - 1.0f, pp[i][j], acc);
        }
        part[jq * NN + i] = acc;
        __syncthreads();
        if (jq == 0)
            E[i] = part[i] + part[NN + i] + part[2 * NN + i] + part[3 * NN + i];
        __syncthreads();
    }

    if (tid < 64) {
        float s = E[tid];
        for (int off = 32; off > 0; off >>= 1) s += __shfl_down(s, off);
        float meanE = __shfl(s, 0) * (1.0f / 64.0f);
        out[b * NN + tid] = logits[b * NN + tid] + meanE;
    }
}

extern "C" void kernel_launch(void* const* d_in, const int* in_sizes, int n_in,
                              void* d_out, int out_size, void* d_ws, size_t ws_size,
                              hipStream_t stream) {
    const float* a      = (const float*)d_in[0];  // [8,64,64,32,32]
    const float* logits = (const float*)d_in[1];  // [8,64]
    const float* Wm     = (const float*)d_in[2];  // [1,64,64]
    float* out  = (float*)d_out;                  // [8,64]

    float* part = (float*)d_ws;                           // [2048][4096] fp32
    float* gram = part + (size_t)BATCH * CH * NN * NN;    // [8][4096]

    gram_partial_kernel<<<BATCH * CH, 256, 0, stream>>>(a, part);
    gram_reduce_kernel<<<(BATCH * NN * NN) / 128, 128, 0, stream>>>(part, gram);
    crf_kernel<<<BATCH, 256, 0, stream>>>(gram, logits, Wm, out);
}

// Round 5
// 224.275 us; speedup vs baseline: 1.1228x; 1.1228x over previous
//
#include <hip/hip_runtime.h>
#include <math.h>

// Problem constants
#define BATCH 8
#define NN 64
#define DD 65536            // 64*32*32 feature length (contiguous per [b,n])
#define BPB 64              // blocks per batch -> grid = 512
#define NBLK (BATCH * BPB)
#define KC (DD / BPB)       // 1024 K per block
#define KW (KC / 4)         // 256 K per wave (waves split K, not M!)
#define KSTEPS (KW / 32)    // 8 MFMA K-steps per wave

typedef float  floatx4 __attribute__((ext_vector_type(4)));
typedef __bf16 bf16x8  __attribute__((ext_vector_type(8)));

// Pack 8 fp32 -> 8 bf16 via v_perm_b32 (truncation; bias cancels in the
// scale-invariant cosine ratio — validated R3/R4: absmax 1.5e-5).
static __device__ __forceinline__ bf16x8 cvt8(float4 lo, float4 hi) {
    const unsigned sel = 0x07060302u;
    union { unsigned u[4]; bf16x8 v; } r;
    r.u[0] = __builtin_amdgcn_perm(__float_as_uint(lo.y), __float_as_uint(lo.x), sel);
    r.u[1] = __builtin_amdgcn_perm(__float_as_uint(lo.w), __float_as_uint(lo.z), sel);
    r.u[2] = __builtin_amdgcn_perm(__float_as_uint(hi.y), __float_as_uint(hi.x), sel);
    r.u[3] = __builtin_amdgcn_perm(__float_as_uint(hi.w), __float_as_uint(hi.z), sel);
    return r.v;
}

// ---------------------------------------------------------------------------
// Stage 1: per-chunk partial Gram. Waves split the K-range; EACH WAVE computes
// the FULL 64x64 tile grid (16 accumulators) from its 4 fragments per step —
// every input byte is loaded exactly ONCE (R4 was 4x redundant and saturated
// the ~10 B/cyc/CU load pipe with L2 re-reads).
// MFMA(f_i, f_j) -> D[4q+r][m] = G[16i+4q+r][16j+m]  (m89 layout, validated
// R1-R4). No symmetry assumption needed. No barriers in the main loop; one
// cross-wave LDS reduce at the end.
// ---------------------------------------------------------------------------
__global__ __launch_bounds__(256) void gram_partial_kernel(const float* __restrict__ a,
                                                           float* __restrict__ part) {
    __shared__ __align__(16) float red[3][16][64][4];   // 48 KB

    const int bid = blockIdx.x;
    const int b = bid >> 6;           // / BPB
    const int c = bid & (BPB - 1);

    const int tid  = threadIdx.x;
    const int w    = tid >> 6;        // wave id 0..3 -> K-subchunk
    const int lane = tid & 63;
    const int m    = lane & 15;
    const int q    = lane >> 4;

    const float* base = a + (size_t)b * NN * DD + (size_t)c * KC + (size_t)w * KW
                          + (size_t)m * DD + q * 8;
    const float* p0 = base;                       // band 0 rows  0..15
    const float* p1 = base + (size_t)16 * DD;     // band 1 rows 16..31
    const float* p2 = base + (size_t)32 * DD;     // band 2 rows 32..47
    const float* p3 = base + (size_t)48 * DD;     // band 3 rows 48..63

    floatx4 acc[16];
    #pragma unroll
    for (int i = 0; i < 16; ++i) acc[i] = (floatx4)0.0f;

    float4 A0, A1, A2, A3, A4, A5, A6, A7;   // buffer A
    float4 B0, B1, B2, B3, B4, B5, B6, B7;   // buffer B

#define LOADSET(R0,R1,R2,R3,R4,R5,R6,R7, o)                                \
    R0 = *(const float4*)(p0 + (o));  R1 = *(const float4*)(p0 + (o) + 4); \
    R2 = *(const float4*)(p1 + (o));  R3 = *(const float4*)(p1 + (o) + 4); \
    R4 = *(const float4*)(p2 + (o));  R5 = *(const float4*)(p2 + (o) + 4); \
    R6 = *(const float4*)(p3 + (o));  R7 = *(const float4*)(p3 + (o) + 4);

#define MFMASET(R0,R1,R2,R3,R4,R5,R6,R7)                                   \
    {                                                                      \
        bf16x8 f0 = cvt8(R0, R1);                                          \
        bf16x8 f1 = cvt8(R2, R3);                                          \
        bf16x8 f2 = cvt8(R4, R5);                                          \
        bf16x8 f3 = cvt8(R6, R7);                                          \
        acc[ 0] = __builtin_amdgcn_mfma_f32_16x16x32_bf16(f0, f0, acc[ 0], 0, 0, 0); \
        acc[ 1] = __builtin_amdgcn_mfma_f32_16x16x32_bf16(f0, f1, acc[ 1], 0, 0, 0); \
        acc[ 2] = __builtin_amdgcn_mfma_f32_16x16x32_bf16(f0, f2, acc[ 2], 0, 0, 0); \
        acc[ 3] = __builtin_amdgcn_mfma_f32_16x16x32_bf16(f0, f3, acc[ 3], 0, 0, 0); \
        acc[ 4] = __builtin_amdgcn_mfma_f32_16x16x32_bf16(f1, f0, acc[ 4], 0, 0, 0); \
        acc[ 5] = __builtin_amdgcn_mfma_f32_16x16x32_bf16(f1, f1, acc[ 5], 0, 0, 0); \
        acc[ 6] = __builtin_amdgcn_mfma_f32_16x16x32_bf16(f1, f2, acc[ 6], 0, 0, 0); \
        acc[ 7] = __builtin_amdgcn_mfma_f32_16x16x32_bf16(f1, f3, acc[ 7], 0, 0, 0); \
        acc[ 8] = __builtin_amdgcn_mfma_f32_16x16x32_bf16(f2, f0, acc[ 8], 0, 0, 0); \
        acc[ 9] = __builtin_amdgcn_mfma_f32_16x16x32_bf16(f2, f1, acc[ 9], 0, 0, 0); \
        acc[10] = __builtin_amdgcn_mfma_f32_16x16x32_bf16(f2, f2, acc[10], 0, 0, 0); \
        acc[11] = __builtin_amdgcn_mfma_f32_16x16x32_bf16(f2, f3, acc[11], 0, 0, 0); \
        acc[12] = __builtin_amdgcn_mfma_f32_16x16x32_bf16(f3, f0, acc[12], 0, 0, 0); \
        acc[13] = __builtin_amdgcn_mfma_f32_16x16x32_bf16(f3, f1, acc[13], 0, 0, 0); \
        acc[14] = __builtin_amdgcn_mfma_f32_16x16x32_bf16(f3, f2, acc[14], 0, 0, 0); \
        acc[15] = __builtin_amdgcn_mfma_f32_16x16x32_bf16(f3, f3, acc[15], 0, 0, 0); \
    }

    LOADSET(A0,A1,A2,A3,A4,A5,A6,A7, 0)
    #pragma unroll
    for (int s = 0; s < KSTEPS; s += 2) {
        LOADSET(B0,B1,B2,B3,B4,B5,B6,B7, (s + 1) * 32)
        MFMASET(A0,A1,A2,A3,A4,A5,A6,A7)
        if (s + 2 < KSTEPS) { LOADSET(A0,A1,A2,A3,A4,A5,A6,A7, (s + 2) * 32) }
        MFMASET(B0,B1,B2,B3,B4,B5,B6,B7)
    }
#undef LOADSET
#undef MFMASET

    // Cross-wave reduce: waves 1..3 dump accs to LDS; wave 0 sums + stores.
    if (w > 0) {
        #pragma unroll
        for (int t = 0; t < 16; ++t)
            *(floatx4*)&red[w - 1][t][lane][0] = acc[t];
    }
    __syncthreads();
    if (w == 0) {
        #pragma unroll
        for (int t = 0; t < 16; ++t) {
            floatx4 r0 = *(const floatx4*)&red[0][t][lane][0];
            floatx4 r1 = *(const floatx4*)&red[1][t][lane][0];
            floatx4 r2 = *(const floatx4*)&red[2][t][lane][0];
            acc[t] += (r0 + r1) + r2;
        }
        // slot t = i*4+j holds G[16i + 4q + r][16j + m]
        float* pg = part + (size_t)bid * (NN * NN);
        #pragma unroll
        for (int t = 0; t < 16; ++t) {
            float* tp = pg + t * 256 + m;
            #pragma unroll
            for (int r = 0; r < 4; ++r)
                tp[(q * 4 + r) * 16] = acc[t][r];
        }
    }
}

// ---------------------------------------------------------------------------
// Stage 1b: reduce BPB=64 partials per batch -> gram[8][64*64] (row-major).
// 256 blocks x 128 threads; 4 accumulators keep loads in flight.
// ---------------------------------------------------------------------------
__global__ __launch_bounds__(128) void gram_reduce_kernel(const float* __restrict__ part,
                                                          float* __restrict__ gram) {
    const int gid = blockIdx.x * 128 + threadIdx.x;   // 0 .. 8*4096-1
    const int b   = gid >> 12;
    const int idx = gid & 4095;
    const int i   = idx >> 6;
    const int j   = idx & 63;
    const int off = ((i >> 4) * 4 + (j >> 4)) * 256 + (i & 15) * 16 + (j & 15);
    const float* p = part + (size_t)b * BPB * (NN * NN) + off;

    float s0 = 0.f, s1 = 0.f, s2 = 0.f, s3 = 0.f;
    #pragma unroll 4
    for (int c = 0; c < BPB; c += 4) {
        s0 += p[(size_t)(c + 0) * (NN * NN)];
        s1 += p[(size_t)(c + 1) * (NN * NN)];
        s2 += p[(size_t)(c + 2) * (NN * NN)];
        s3 += p[(size_t)(c + 3) * (NN * NN)];
    }
    gram[gid] = (s0 + s1) + (s2 + s3);
}

// ---------------------------------------------------------------------------
// Stage 2: per-batch CRF iterations. 8 blocks x 256 threads.
// ---------------------------------------------------------------------------
__global__ __launch_bounds__(256) void crf_kernel(const float* __restrict__ gram,
                                                  const float* __restrict__ logits,
                                                  const float* __restrict__ Wm,
                                                  float* __restrict__ out) {
    __shared__ float pp[NN][NN + 1];
    __shared__ float E[NN];
    __shared__ float nrm[NN];
    __shared__ float part[4 * NN];

    const int b  = blockIdx.x;
    const int tid = threadIdx.x;
    const int i  = tid & 63;
    const int jq = tid >> 6;
    const float* g = gram + b * NN * NN;

    if (jq == 0) nrm[i] = sqrtf(g[i * NN + i]);
    E[i] = 0.0f;
    __syncthreads();

    const float ni = nrm[i];
    for (int jj = 0; jj < 16; ++jj) {
        int j = jq * 16 + jj;
        float wsym = 0.5f * (Wm[i * NN + j] + Wm[j * NN + i]);
        pp[i][j] = g[i * NN + j] / (ni * nrm[j] + 1e-6f) * wsym;
    }
    const float li = logits[b * NN + i];
    __syncthreads();

    for (int it = 0; it < 10; ++it) {
        float acc = 0.0f;
        for (int jj = 0; jj < 16; ++jj) {
            int j = jq * 16 + jj;
            float t = li + E[j];
            float s = 1.0f / (1.0f + expf(-t));
            acc = fmaf(2.0f * s - 1.0f, pp[i][j], acc);
        }
        part[jq * NN + i] = acc;
        __syncthreads();
        if (jq == 0)
            E[i] = part[i] + part[NN + i] + part[2 * NN + i] + part[3 * NN + i];
        __syncthreads();
    }

    if (tid < 64) {
        float s = E[tid];
        for (int off = 32; off > 0; off >>= 1) s += __shfl_down(s, off);
        float meanE = __shfl(s, 0) * (1.0f / 64.0f);
        out[b * NN + tid] = logits[b * NN + tid] + meanE;
    }
}

extern "C" void kernel_launch(void* const* d_in, const int* in_sizes, int n_in,
                              void* d_out, int out_size, void* d_ws, size_t ws_size,
                              hipStream_t stream) {
    const float* a      = (const float*)d_in[0];  // [8,64,64,32,32]
    const float* logits = (const float*)d_in[1];  // [8,64]
    const float* Wm     = (const float*)d_in[2];  // [1,64,64]
    float* out  = (float*)d_out;                  // [8,64]

    float* part = (float*)d_ws;                           // [512][4096] fp32
    float* gram = part + (size_t)NBLK * NN * NN;          // [8][4096]

    gram_partial_kernel<<<NBLK, 256, 0, stream>>>(a, part);
    gram_reduce_kernel<<<(BATCH * NN * NN) / 128, 128, 0, stream>>>(part, gram);
    crf_kernel<<<BATCH, 256, 0, stream>>>(gram, logits, Wm, out);
}

// Round 6
// 217.791 us; speedup vs baseline: 1.1563x; 1.0298x over previous
//
#include <hip/hip_runtime.h>
#include <math.h>

// Problem constants
#define BATCH 8
#define NN 64
#define DD 65536            // 64*32*32 feature length (contiguous per [b,n])
#define BPB 64              // blocks per batch -> grid = 512
#define NBLK (BATCH * BPB)
#define KC (DD / BPB)       // 1024 K per block
#define KW (KC / 4)         // 256 K per wave (waves split K)
#define KSTEPS (KW / 32)    // 8 MFMA K-steps per wave
#define NTRI 10             // upper-triangle 16x16 tiles of the 64x64 Gram
#define PSZ (NTRI * 256)    // floats per partial (2560)

typedef float  floatx4 __attribute__((ext_vector_type(4)));
typedef __bf16 bf16x8  __attribute__((ext_vector_type(8)));

// Pack 8 fp32 -> 8 bf16 via v_perm_b32 (truncation; bias cancels in the
// scale-invariant cosine ratio — validated R3-R5: absmax 1.5e-5).
static __device__ __forceinline__ bf16x8 cvt8(float4 lo, float4 hi) {
    const unsigned sel = 0x07060302u;
    union { unsigned u[4]; bf16x8 v; } r;
    r.u[0] = __builtin_amdgcn_perm(__float_as_uint(lo.y), __float_as_uint(lo.x), sel);
    r.u[1] = __builtin_amdgcn_perm(__float_as_uint(lo.w), __float_as_uint(lo.z), sel);
    r.u[2] = __builtin_amdgcn_perm(__float_as_uint(hi.y), __float_as_uint(hi.x), sel);
    r.u[3] = __builtin_amdgcn_perm(__float_as_uint(hi.w), __float_as_uint(hi.z), sel);
    return r.v;
}

// ---------------------------------------------------------------------------
// Stage 1: per-chunk partial Gram, upper-triangle tiles only.
// Waves split the K-range (each byte loaded exactly once — R5). A K-partial
// Gram is itself symmetric, so tiles (i,j), i<=j suffice: 10 accumulators
// (40 VGPR) instead of 16 (64) -> register dbuf fits under the
// __launch_bounds__(256,3) cap (12 waves/CU) without spills.
// MFMA(f_i, f_j) -> D[4q+r][m] = G[16i+4q+r][16j+m]  (m89 layout, validated
// R1-R5). No barriers in the main loop; one cross-wave LDS reduce at the end.
// ---------------------------------------------------------------------------
__global__ __launch_bounds__(256, 3) void gram_partial_kernel(const float* __restrict__ a,
                                                              float* __restrict__ part) {
    __shared__ __align__(16) float red[3][NTRI][64][4];   // 30 KB

    const int bid = blockIdx.x;
    const int b = bid >> 6;           // / BPB
    const int c = bid & (BPB - 1);

    const int tid  = threadIdx.x;
    const int w    = tid >> 6;        // wave id 0..3 -> K-subchunk
    const int lane = tid & 63;
    const int m    = lane & 15;
    const int q    = lane >> 4;

    const float* base = a + (size_t)b * NN * DD + (size_t)c * KC + (size_t)w * KW
                          + (size_t)m * DD + q * 8;
    const float* p0 = base;                       // rows  0..15
    const float* p1 = base + (size_t)16 * DD;     // rows 16..31
    const float* p2 = base + (size_t)32 * DD;     // rows 32..47
    const float* p3 = base + (size_t)48 * DD;     // rows 48..63

    floatx4 acc[NTRI];
    #pragma unroll
    for (int i = 0; i < NTRI; ++i) acc[i] = (floatx4)0.0f;

    float4 A0, A1, A2, A3, A4, A5, A6, A7;   // buffer A
    float4 B0, B1, B2, B3, B4, B5, B6, B7;   // buffer B

#define LOADSET(R0,R1,R2,R3,R4,R5,R6,R7, o)                                \
    R0 = *(const float4*)(p0 + (o));  R1 = *(const float4*)(p0 + (o) + 4); \
    R2 = *(const float4*)(p1 + (o));  R3 = *(const float4*)(p1 + (o) + 4); \
    R4 = *(const float4*)(p2 + (o));  R5 = *(const float4*)(p2 + (o) + 4); \
    R6 = *(const float4*)(p3 + (o));  R7 = *(const float4*)(p3 + (o) + 4);

    // acc slots: 0:(0,0) 1:(0,1) 2:(0,2) 3:(0,3) 4:(1,1) 5:(1,2) 6:(1,3)
    //            7:(2,2) 8:(2,3) 9:(3,3)
#define MFMASET(R0,R1,R2,R3,R4,R5,R6,R7)                                   \
    {                                                                      \
        bf16x8 f0 = cvt8(R0, R1);                                          \
        bf16x8 f1 = cvt8(R2, R3);                                          \
        bf16x8 f2 = cvt8(R4, R5);                                          \
        bf16x8 f3 = cvt8(R6, R7);                                          \
        acc[0] = __builtin_amdgcn_mfma_f32_16x16x32_bf16(f0, f0, acc[0], 0, 0, 0); \
        acc[1] = __builtin_amdgcn_mfma_f32_16x16x32_bf16(f0, f1, acc[1], 0, 0, 0); \
        acc[2] = __builtin_amdgcn_mfma_f32_16x16x32_bf16(f0, f2, acc[2], 0, 0, 0); \
        acc[3] = __builtin_amdgcn_mfma_f32_16x16x32_bf16(f0, f3, acc[3], 0, 0, 0); \
        acc[4] = __builtin_amdgcn_mfma_f32_16x16x32_bf16(f1, f1, acc[4], 0, 0, 0); \
        acc[5] = __builtin_amdgcn_mfma_f32_16x16x32_bf16(f1, f2, acc[5], 0, 0, 0); \
        acc[6] = __builtin_amdgcn_mfma_f32_16x16x32_bf16(f1, f3, acc[6], 0, 0, 0); \
        acc[7] = __builtin_amdgcn_mfma_f32_16x16x32_bf16(f2, f2, acc[7], 0, 0, 0); \
        acc[8] = __builtin_amdgcn_mfma_f32_16x16x32_bf16(f2, f3, acc[8], 0, 0, 0); \
        acc[9] = __builtin_amdgcn_mfma_f32_16x16x32_bf16(f3, f3, acc[9], 0, 0, 0); \
    }

    LOADSET(A0,A1,A2,A3,A4,A5,A6,A7, 0)
    #pragma unroll
    for (int s = 0; s < KSTEPS; s += 2) {
        LOADSET(B0,B1,B2,B3,B4,B5,B6,B7, (s + 1) * 32)
        MFMASET(A0,A1,A2,A3,A4,A5,A6,A7)
        if (s + 2 < KSTEPS) { LOADSET(A0,A1,A2,A3,A4,A5,A6,A7, (s + 2) * 32) }
        MFMASET(B0,B1,B2,B3,B4,B5,B6,B7)
    }
#undef LOADSET
#undef MFMASET

    // Cross-wave reduce: waves 1..3 dump accs to LDS; wave 0 sums + stores.
    if (w > 0) {
        #pragma unroll
        for (int t = 0; t < NTRI; ++t)
            *(floatx4*)&red[w - 1][t][lane][0] = acc[t];
    }
    __syncthreads();
    if (w == 0) {
        #pragma unroll
        for (int t = 0; t < NTRI; ++t) {
            floatx4 r0 = *(const floatx4*)&red[0][t][lane][0];
            floatx4 r1 = *(const floatx4*)&red[1][t][lane][0];
            floatx4 r2 = *(const floatx4*)&red[2][t][lane][0];
            acc[t] += (r0 + r1) + r2;
        }
        // slot t holds G[16*ib + 4q + r][16*jb + m] for its (ib,jb)
        float* pg = part + (size_t)bid * PSZ;
        #pragma unroll
        for (int t = 0; t < NTRI; ++t) {
            float* tp = pg + t * 256 + m;
            #pragma unroll
            for (int r = 0; r < 4; ++r)
                tp[(q * 4 + r) * 16] = acc[t][r];
        }
    }
}

// ---------------------------------------------------------------------------
// Stage 1b: reduce BPB=64 tri-partials per batch -> gram[8][64*64] row-major.
// Lower triangle reconstructed by reading the transposed slot (each K-partial
// Gram is symmetric, so this is exact).
// ---------------------------------------------------------------------------
__global__ __launch_bounds__(128) void gram_reduce_kernel(const float* __restrict__ part,
                                                          float* __restrict__ gram) {
    const int gid = blockIdx.x * 128 + threadIdx.x;   // 0 .. 8*4096-1
    const int b   = gid >> 12;
    const int idx = gid & 4095;
    const int i   = idx >> 6;
    const int j   = idx & 63;
    const int ti  = i >> 4, tj = j >> 4;
    const int ib  = ti <= tj ? ti : tj;
    const int jb  = ti <= tj ? tj : ti;
    const int slot = ib * 4 - (ib * (ib - 1)) / 2 + (jb - ib);
    const int rr  = (ti <= tj) ? (i & 15) : (j & 15);
    const int cc  = (ti <= tj) ? (j & 15) : (i & 15);
    const int off = slot * 256 + rr * 16 + cc;
    const float* p = part + (size_t)b * BPB * PSZ + off;

    float s0 = 0.f, s1 = 0.f, s2 = 0.f, s3 = 0.f;
    #pragma unroll 4
    for (int c = 0; c < BPB; c += 4) {
        s0 += p[(size_t)(c + 0) * PSZ];
        s1 += p[(size_t)(c + 1) * PSZ];
        s2 += p[(size_t)(c + 2) * PSZ];
        s3 += p[(size_t)(c + 3) * PSZ];
    }
    gram[gid] = (s0 + s1) + (s2 + s3);
}

// ---------------------------------------------------------------------------
// Stage 2: per-batch CRF iterations. 8 blocks x 256 threads.
// ---------------------------------------------------------------------------
__global__ __launch_bounds__(256) void crf_kernel(const float* __restrict__ gram,
                                                  const float* __restrict__ logits,
                                                  const float* __restrict__ Wm,
                                                  float* __restrict__ out) {
    __shared__ float pp[NN][NN + 1];
    __shared__ float E[NN];
    __shared__ float nrm[NN];
    __shared__ float part[4 * NN];

    const int b  = blockIdx.x;
    const int tid = threadIdx.x;
    const int i  = tid & 63;
    const int jq = tid >> 6;
    const float* g = gram + b * NN * NN;

    if (jq == 0) nrm[i] = sqrtf(g[i * NN + i]);
    E[i] = 0.0f;
    __syncthreads();

    const float ni = nrm[i];
    for (int jj = 0; jj < 16; ++jj) {
        int j = jq * 16 + jj;
        float wsym = 0.5f * (Wm[i * NN + j] + Wm[j * NN + i]);
        pp[i][j] = g[i * NN + j] / (ni * nrm[j] + 1e-6f) * wsym;
    }
    const float li = logits[b * NN + i];
    __syncthreads();

    for (int it = 0; it < 10; ++it) {
        float acc = 0.0f;
        for (int jj = 0; jj < 16; ++jj) {
            int j = jq * 16 + jj;
            float t = li + E[j];
            float s = 1.0f / (1.0f + expf(-t));
            acc = fmaf(2.0f * s - 1.0f, pp[i][j], acc);
        }
        part[jq * NN + i] = acc;
        __syncthreads();
        if (jq == 0)
            E[i] = part[i] + part[NN + i] + part[2 * NN + i] + part[3 * NN + i];
        __syncthreads();
    }

    if (tid < 64) {
        float s = E[tid];
        for (int off = 32; off > 0; off >>= 1) s += __shfl_down(s, off);
        float meanE = __shfl(s, 0) * (1.0f / 64.0f);
        out[b * NN + tid] = logits[b * NN + tid] + meanE;
    }
}

extern "C" void kernel_launch(void* const* d_in, const int* in_sizes, int n_in,
                              void* d_out, int out_size, void* d_ws, size_t ws_size,
                              hipStream_t stream) {
    const float* a      = (const float*)d_in[0];  // [8,64,64,32,32]
    const float* logits = (const float*)d_in[1];  // [8,64]
    const float* Wm     = (const float*)d_in[2];  // [1,64,64]
    float* out  = (float*)d_out;                  // [8,64]

    float* part = (float*)d_ws;                           // [512][2560] fp32
    float* gram = part + (size_t)NBLK * PSZ;              // [8][4096]

    gram_partial_kernel<<<NBLK, 256, 0, stream>>>(a, part);
    gram_reduce_kernel<<<(BATCH * NN * NN) / 128, 128, 0, stream>>>(part, gram);
    crf_kernel<<<BATCH, 256, 0, stream>>>(gram, logits, Wm, out);
}